// Round 1
// baseline (20.108 us; speedup 1.0000x reference)
//
#include <hip/hip_runtime.h>

// SymPBC feature kernel for MI355X.
// Reference math (M=2 dual-pol collapses _triple's pol-swap to a sum over q):
//   B1 = sum_q E[w-n,q]*conj(E[w-m-n,q]);  B2 = sum_q E[w+n,q]*conj(E[w+m+n,q])
//   T1[p] = B1*E[w-m,p] + B2*E[w+m,p]
//   B3 = sum_q E[w-m,q]*conj(E[w-m-n,q]);  B4 = sum_q E[w+m,q]*conj(E[w+m+n,q])
//   T2[p] = B3*E[w-n,p] + B4*E[w+n,p]
//   F = w1*T1 + w2*T2;  w1 = 0.5 iff (m==0 && n==0) else 1;  w2 = (n > |m|)
// Output layout: out[b][w][p][s][c], c = {re, im}, float32.

constexpr int W = 16384;
constexpr int WMASK = W - 1;
constexpr int NB = 2;            // batch
constexpr int S = 118;
constexpr int HALO = 26;         // max |m+n| over the index set
constexpr int TILE_W = 16;       // w positions per block
constexpr int LDSW = TILE_W + 2 * HALO;   // 68 staged positions

struct C2 { float re, im; };

// Decode s -> (m, n) matching Python iteration order:
// for m in -25..25: for n in -25..25: keep if |m*n| <= 25 and n >= |m|.
// Valid m in [-5,5]; per-m count: m=0 -> 26 (n=0..25); else min(25, 25/|m|) - |m| + 1.
// Group starts: 0,1,4,10,21,46,72,97,108,114,117 (total 118).
__device__ inline void decode_s(int s, int& m_out, int& n_out) {
    int start = 0;
    int rm = 0, rn = 0;
    #pragma unroll
    for (int mm = -5; mm <= 5; ++mm) {
        const int am = mm < 0 ? -mm : mm;
        int nmax = (mm == 0) ? 25 : (25 / am);
        if (nmax > 25) nmax = 25;
        const int nmin = am;             // n >= |m| (n >= 0 for m==0)
        const int cnt = nmax - nmin + 1;
        const bool in = (s >= start) && (s < start + cnt);
        if (in) { rm = mm; rn = nmin + (s - start); }
        start += cnt;
    }
    m_out = rm; n_out = rn;
}

// bracket(Xa, Xb) = sum_q Xa_q * conj(Xb_q), X layout = (re0, im0, re1, im1)
__device__ inline C2 bracket(const float4& a, const float4& b) {
    C2 r;
    r.re = a.x * b.x + a.y * b.y + a.z * b.z + a.w * b.w;
    r.im = a.y * b.x - a.x * b.y + a.w * b.z - a.z * b.w;
    return r;
}

// Compute F for one (w, s): returns (re_p0, im_p0, re_p1, im_p1)
__device__ inline float4 compute_ws(const float4* lds, int ci, int m, int n) {
    const float4 Am  = lds[ci - m];        // E[w-m]
    const float4 Ap  = lds[ci + m];        // E[w+m]
    const float4 An  = lds[ci - n];        // E[w-n]
    const float4 Bn  = lds[ci + n];        // E[w+n]
    const float4 Amn = lds[ci - m - n];    // E[w-(m+n)]
    const float4 Bmn = lds[ci + m + n];    // E[w+(m+n)]

    const C2 B1 = bracket(An, Amn);
    const C2 B2 = bracket(Bn, Bmn);

    // T1[p] = B1 * E[w-m, p] + B2 * E[w+m, p]
    float r0 = B1.re * Am.x - B1.im * Am.y + B2.re * Ap.x - B2.im * Ap.y;
    float i0 = B1.re * Am.y + B1.im * Am.x + B2.re * Ap.y + B2.im * Ap.x;
    float r1 = B1.re * Am.z - B1.im * Am.w + B2.re * Ap.z - B2.im * Ap.w;
    float i1 = B1.re * Am.w + B1.im * Am.z + B2.re * Ap.w + B2.im * Ap.z;

    const int am = m < 0 ? -m : m;
    const float w1 = (m == 0 && n == 0) ? 0.5f : 1.0f;
    r0 *= w1; i0 *= w1; r1 *= w1; i1 *= w1;

    // T2 scaled by w2 (avoid divergent branch: fold w2 into the brackets)
    const float w2 = (n > am) ? 1.0f : 0.0f;
    C2 B3 = bracket(Am, Amn);
    C2 B4 = bracket(Ap, Bmn);
    B3.re *= w2; B3.im *= w2; B4.re *= w2; B4.im *= w2;

    // T2[p] = B3 * E[w-n, p] + B4 * E[w+n, p]
    r0 += B3.re * An.x - B3.im * An.y + B4.re * Bn.x - B4.im * Bn.y;
    i0 += B3.re * An.y + B3.im * An.x + B4.re * Bn.y + B4.im * Bn.x;
    r1 += B3.re * An.z - B3.im * An.w + B4.re * Bn.z - B4.im * Bn.w;
    i1 += B3.re * An.w + B3.im * An.z + B4.re * Bn.w + B4.im * Bn.z;

    return make_float4(r0, i0, r1, i1);
}

__global__ __launch_bounds__(256) void sympbc_kernel(
    const float* __restrict__ Er, const float* __restrict__ Ei,
    float* __restrict__ out)
{
    __shared__ float4 lds[LDSW];

    const int tid = threadIdx.x;
    const int b = blockIdx.y;
    const int tile0 = blockIdx.x * TILE_W;

    // Stage (TILE_W + 2*HALO) positions of interleaved complex dual-pol E.
    if (tid < LDSW) {
        const int gw = (tile0 - HALO + tid) & WMASK;
        const size_t gi = ((size_t)b * W + gw) * 2;
        const float2 r = *reinterpret_cast<const float2*>(Er + gi);
        const float2 i = *reinterpret_cast<const float2*>(Ei + gi);
        lds[tid] = make_float4(r.x, i.x, r.y, i.y);
    }
    __syncthreads();

    const int sp = tid & 63;        // s-pair index: covers s = 2*sp, 2*sp+1
    const int wsub = tid >> 6;      // 0..3, one w per wave per pass
    const bool active = (sp < 59);  // 59 pairs cover s = 0..117

    const int s0 = 2 * sp;
    int m0, n0, m1, n1;
    decode_s(s0, m0, n0);
    decode_s(s0 + 1, m1, n1);

    #pragma unroll
    for (int it = 0; it < TILE_W / 4; ++it) {
        const int wl = wsub + 4 * it;
        const int ci = HALO + wl;
        const int wg = tile0 + wl;
        if (active) {
            const float4 F0 = compute_ws(lds, ci, m0, n0);
            const float4 F1 = compute_ws(lds, ci, m1, n1);
            // out flat index: (((b*W + w)*2 + p)*S + s)*2 + c
            float* obase = out + ((size_t)b * W + wg) * (2 * S * 2);
            // p = 0: (re_s0, im_s0, re_s1, im_s1) at s0*2
            *reinterpret_cast<float4*>(obase + (size_t)s0 * 2) =
                make_float4(F0.x, F0.y, F1.x, F1.y);
            // p = 1: offset by S*2
            *reinterpret_cast<float4*>(obase + (size_t)(S * 2) + (size_t)s0 * 2) =
                make_float4(F0.z, F0.w, F1.z, F1.w);
        }
    }
}

extern "C" void kernel_launch(void* const* d_in, const int* in_sizes, int n_in,
                              void* d_out, int out_size, void* d_ws, size_t ws_size,
                              hipStream_t stream) {
    const float* Er = (const float*)d_in[0];
    const float* Ei = (const float*)d_in[1];
    float* out = (float*)d_out;
    dim3 grid(W / TILE_W, NB);
    sympbc_kernel<<<grid, dim3(256), 0, stream>>>(Er, Ei, out);
}